// Round 2
// baseline (825.481 us; speedup 1.0000x reference)
//
#include <hip/hip_runtime.h>
#include <hip/hip_bf16.h>
#include <math.h>

#define DIM 128
#define NSLOT 8
#define NTOK 4096
#define NB 32
#define CHUNK 256
#define NCH (NTOK / CHUNK)   // 16
#define LN_EPS 1e-3f
#define ATT_EPS 1e-8f
#define SCALE 0.08838834764831845f  // 128^-0.5

__device__ __forceinline__ float bf2f(unsigned short u) {
  return __uint_as_float(((unsigned)u) << 16);
}
__device__ __forceinline__ unsigned short f2bf(float f) {
  unsigned u = __float_as_uint(f);
  unsigned r = (u + 0x7FFFu + ((u >> 16) & 1u)) >> 16;
  return (unsigned short)r;
}

// ---------------------------------------------------------------------------
// Kernel 1: jax.random.normal(key(42), (32,8,128)) with PARTITIONABLE threefry
// (JAX >= 0.4.30 default): per element i, counter pair = (hi32(i)=0, lo32(i)=i),
// output bits = out0 ^ out1.  slots = mu + exp(log_sigma)*noise.
// ---------------------------------------------------------------------------
__device__ __forceinline__ float erfinv_like_xla(float x) {
  double xd = (double)x;
  double w = -log1p(-xd * xd);
  double p;
  if (w < 5.0) {
    w = w - 2.5;
    p = 2.81022636e-08;
    p = 3.43273939e-07 + p * w;
    p = -3.5233877e-06 + p * w;
    p = -4.39150654e-06 + p * w;
    p = 0.00021858087 + p * w;
    p = -0.00125372503 + p * w;
    p = -0.00417768164 + p * w;
    p = 0.246640727 + p * w;
    p = 1.50140941 + p * w;
  } else {
    w = sqrt(w) - 3.0;
    p = -0.000200214257;
    p = 0.000100950558 + p * w;
    p = 0.00134934322 + p * w;
    p = -0.00367342844 + p * w;
    p = 0.00573950773 + p * w;
    p = -0.0076224613 + p * w;
    p = 0.00943887047 + p * w;
    p = 1.00167406 + p * w;
    p = 2.83297682 + p * w;
  }
  return (float)(p * xd);
}

__global__ __launch_bounds__(256) void k_init_slots(
    const float* __restrict__ mu, const float* __restrict__ lsig,
    float* __restrict__ slots) {
  int t = blockIdx.x * blockDim.x + threadIdx.x;  // 0..32767
  if (t >= NB * NSLOT * DIM) return;
  uint32_t x0 = 0u, x1 = (uint32_t)t;
  uint32_t k0 = 0u, k1 = 42u;
  uint32_t ks[3] = {k0, k1, k0 ^ k1 ^ 0x1BD11BDAu};
  x0 += ks[0];
  x1 += ks[1];
  const int rot[2][4] = {{13, 15, 26, 6}, {17, 29, 16, 24}};
#pragma unroll
  for (int blk = 0; blk < 5; ++blk) {
    const int* r = rot[blk & 1];
#pragma unroll
    for (int j = 0; j < 4; ++j) {
      x0 += x1;
      x1 = (x1 << r[j]) | (x1 >> (32 - r[j]));
      x1 ^= x0;
    }
    x0 += ks[(blk + 1) % 3];
    x1 += ks[(blk + 2) % 3] + (uint32_t)(blk + 1);
  }
  uint32_t bits = x0 ^ x1;  // partitionable: fold 64 output bits -> 32
  float f = __uint_as_float((bits >> 9) | 0x3F800000u) - 1.0f;
  const float mn = __uint_as_float(0xBF7FFFFFu);  // nextafter(-1,0)
  float u = fmaxf(f * 2.0f + mn, mn);             // (hi-lo) rounds to 2.0f
  float noise = 1.41421356f * erfinv_like_xla(u);
  int d = t & (DIM - 1);
  slots[t] = mu[d] + expf(lsig[d]) * noise;
}

// ---------------------------------------------------------------------------
// Kernel 2: x = LN(inputs); kt[b][e][n], vt[b][e][n] in bf16
// ---------------------------------------------------------------------------
__global__ __launch_bounds__(256) void k_ln_kv(
    const float* __restrict__ inp, const float* __restrict__ Wk,
    const float* __restrict__ Wv, const float* __restrict__ lnw,
    const float* __restrict__ lnb, unsigned short* __restrict__ kt,
    unsigned short* __restrict__ vt) {
  int row = blockIdx.x * blockDim.x + threadIdx.x;  // 0..131071
  int b = row >> 12, n = row & (NTOK - 1);
  float x[DIM];
  const float* src = inp + (size_t)row * DIM;
#pragma unroll
  for (int d4 = 0; d4 < DIM / 4; ++d4) {
    float4 v = *reinterpret_cast<const float4*>(src + d4 * 4);
    x[d4 * 4 + 0] = v.x; x[d4 * 4 + 1] = v.y;
    x[d4 * 4 + 2] = v.z; x[d4 * 4 + 3] = v.w;
  }
  float mean = 0.0f;
#pragma unroll
  for (int d = 0; d < DIM; ++d) mean += x[d];
  mean *= (1.0f / DIM);
  float var = 0.0f;
#pragma unroll
  for (int d = 0; d < DIM; ++d) {
    float c = x[d] - mean;
    var += c * c;
  }
  var *= (1.0f / DIM);
  float inv = 1.0f / sqrtf(var + LN_EPS);
#pragma unroll
  for (int d = 0; d < DIM; ++d) x[d] = (x[d] - mean) * inv * lnw[d] + lnb[d];

  size_t outbase = (size_t)b * DIM * NTOK + n;
  for (int e = 0; e < DIM; ++e) {
    const float* wk = Wk + e * DIM;
    const float* wv = Wv + e * DIM;
    float ak = 0.0f, av = 0.0f;
#pragma unroll
    for (int d = 0; d < DIM; ++d) {
      ak += x[d] * wk[d];
      av += x[d] * wv[d];
    }
    kt[outbase + (size_t)e * NTOK] = f2bf(ak);
    vt[outbase + (size_t)e * NTOK] = f2bf(av);
  }
}

// ---------------------------------------------------------------------------
// Kernel 3: q = LN(slots) @ Wq^T
// ---------------------------------------------------------------------------
__global__ __launch_bounds__(256) void k_qproj(
    const float* __restrict__ slots, const float* __restrict__ Wq,
    const float* __restrict__ lnw, const float* __restrict__ lnb,
    float* __restrict__ q) {
  int b = blockIdx.x, t = threadIdx.x;
  int s = t >> 5, c = t & 31;
  __shared__ __align__(16) float sln[NSLOT][DIM];
  const float* sb = slots + (b * NSLOT + s) * DIM;
  float4 xv = *reinterpret_cast<const float4*>(sb + c * 4);
  float ps = xv.x + xv.y + xv.z + xv.w;
  float pq = xv.x * xv.x + xv.y * xv.y + xv.z * xv.z + xv.w * xv.w;
#pragma unroll
  for (int m = 16; m >= 1; m >>= 1) {
    ps += __shfl_xor(ps, m, 32);
    pq += __shfl_xor(pq, m, 32);
  }
  float mean = ps * (1.0f / DIM);
  float var = fmaxf(pq * (1.0f / DIM) - mean * mean, 0.0f);
  float inv = 1.0f / sqrtf(var + LN_EPS);
  float vals[4] = {xv.x, xv.y, xv.z, xv.w};
#pragma unroll
  for (int ii = 0; ii < 4; ++ii) {
    int d = c * 4 + ii;
    sln[s][d] = (vals[ii] - mean) * inv * lnw[d] + lnb[d];
  }
  __syncthreads();
#pragma unroll
  for (int ii = 0; ii < 4; ++ii) {
    int e = c + 32 * ii;
    const float* w = Wq + e * DIM;
    float acc = 0.0f;
#pragma unroll
    for (int d4 = 0; d4 < DIM / 4; ++d4) {
      float4 w4 = *reinterpret_cast<const float4*>(w + d4 * 4);
      float4 s4 = *reinterpret_cast<const float4*>(&sln[s][d4 * 4]);
      acc += s4.x * w4.x + s4.y * w4.y + s4.z * w4.z + s4.w * w4.w;
    }
    q[(b * NSLOT + s) * DIM + e] = acc;
  }
}

// ---------------------------------------------------------------------------
// Kernel 4: per (batch, chunk): dots -> softmax over slots -> +eps -> partial
// D and N sums.
// ---------------------------------------------------------------------------
__global__ __launch_bounds__(256) void k_attn(
    const float* __restrict__ q, const unsigned short* __restrict__ kt,
    const unsigned short* __restrict__ vt, float* __restrict__ Np,
    float* __restrict__ Dp) {
  int bid = blockIdx.x;
  int b = bid >> 4, ch = bid & 15;
  int tok0 = ch * CHUNK;
  int t = threadIdx.x;
  __shared__ __align__(16) float a_t[CHUNK][NSLOT];

  {  // phase 1: one thread per token
    int j = t;
    const unsigned short* kb = kt + (size_t)b * DIM * NTOK + tok0 + j;
    const float* qb = q + b * NSLOT * DIM;
    float dots[NSLOT];
#pragma unroll
    for (int i = 0; i < NSLOT; ++i) dots[i] = 0.0f;
    for (int d = 0; d < DIM; ++d) {
      float kv = bf2f(kb[(size_t)d * NTOK]);
#pragma unroll
      for (int i = 0; i < NSLOT; ++i) dots[i] += qb[i * DIM + d] * kv;
    }
    float m = -1e30f;
#pragma unroll
    for (int i = 0; i < NSLOT; ++i) {
      dots[i] *= SCALE;
      m = fmaxf(m, dots[i]);
    }
    float ssum = 0.0f;
#pragma unroll
    for (int i = 0; i < NSLOT; ++i) {
      dots[i] = expf(dots[i] - m);
      ssum += dots[i];
    }
    float rs = 1.0f / ssum;
#pragma unroll
    for (int i = 0; i < NSLOT; ++i) a_t[j][i] = dots[i] * rs + ATT_EPS;
  }
  __syncthreads();

  {  // phase 2a: D partials
    int i = t >> 5, c = t & 31;
    float s = 0.0f;
#pragma unroll
    for (int jj = 0; jj < CHUNK / 32; ++jj) s += a_t[c + 32 * jj][i];
#pragma unroll
    for (int m = 16; m >= 1; m >>= 1) s += __shfl_xor(s, m, 32);
    if (c == 0) Dp[(b * NCH + ch) * NSLOT + i] = s;
  }

  {  // phase 2b: N partials; thread owns (d, group of 4 slots)
    int d = t & (DIM - 1), ig = t >> 7;
    const unsigned short* vb = vt + (size_t)(b * DIM + d) * NTOK + tok0;
    float acc0 = 0, acc1 = 0, acc2 = 0, acc3 = 0;
    for (int j4 = 0; j4 < CHUNK / 4; ++j4) {
      ushort4 vv = *reinterpret_cast<const ushort4*>(vb + j4 * 4);
      float vvals[4] = {bf2f(vv.x), bf2f(vv.y), bf2f(vv.z), bf2f(vv.w)};
#pragma unroll
      for (int u = 0; u < 4; ++u) {
        float4 av =
            *reinterpret_cast<const float4*>(&a_t[j4 * 4 + u][ig * 4]);
        acc0 += vvals[u] * av.x;
        acc1 += vvals[u] * av.y;
        acc2 += vvals[u] * av.z;
        acc3 += vvals[u] * av.w;
      }
    }
    size_t base = (size_t)(b * NCH + ch) * NSLOT;
    Np[(base + ig * 4 + 0) * DIM + d] = acc0;
    Np[(base + ig * 4 + 1) * DIM + d] = acc1;
    Np[(base + ig * 4 + 2) * DIM + d] = acc2;
    Np[(base + ig * 4 + 3) * DIM + d] = acc3;
  }
}

// ---------------------------------------------------------------------------
// Kernel 5: reduce partials -> updates; GRU; residual MLP. Block = batch.
// ---------------------------------------------------------------------------
__global__ __launch_bounds__(256) void k_update(
    float* __restrict__ slots, const float* __restrict__ Np,
    const float* __restrict__ Dp, const float* __restrict__ W_ih,
    const float* __restrict__ W_hh, const float* __restrict__ b_ih,
    const float* __restrict__ b_hh, const float* __restrict__ W1,
    const float* __restrict__ b1, const float* __restrict__ W2,
    const float* __restrict__ b2, const float* __restrict__ lnfw,
    const float* __restrict__ lnfb) {
  int b = blockIdx.x, t = threadIdx.x;
  __shared__ __align__(16) float sprev[NSLOT][DIM];
  __shared__ __align__(16) float upd[NSLOT][DIM];
  __shared__ __align__(16) float gxs[NSLOT][3 * DIM];
  __shared__ __align__(16) float ghs[NSLOT][3 * DIM];
  __shared__ __align__(16) float snew[NSLOT][DIM];
  __shared__ __align__(16) float ffin[NSLOT][DIM];
  __shared__ __align__(16) float ffb[NSLOT][DIM];
  __shared__ float dsum[NSLOT];

  float* sl = slots + b * NSLOT * DIM;
#pragma unroll
  for (int r = 0; r < 4; ++r) {
    int idx = t + 256 * r;
    sprev[idx >> 7][idx & (DIM - 1)] = sl[idx];
  }
  if (t < NSLOT) {
    float s = 0.0f;
    for (int c = 0; c < NCH; ++c) s += Dp[(b * NCH + c) * NSLOT + t];
    dsum[t] = s;
  }
  __syncthreads();

  {  // updates = (sum_ch Np) / dsum
    int s = t >> 5, c = t & 31;
#pragma unroll
    for (int ii = 0; ii < 4; ++ii) {
      int d = c + 32 * ii;
      float acc = 0.0f;
      for (int ch = 0; ch < NCH; ++ch)
        acc += Np[((size_t)(b * NCH + ch) * NSLOT + s) * DIM + d];
      upd[s][d] = acc / dsum[s];
    }
  }
  __syncthreads();

  // GRU gemms
  for (int g = 0; g < 12; ++g) {
    int o = g * 256 + t;  // 0..3071
    int s = o / 384, e = o % 384;
    const float* wi = W_ih + e * DIM;
    const float* wh = W_hh + e * DIM;
    float ax = 0.0f, ah = 0.0f;
#pragma unroll
    for (int d4 = 0; d4 < DIM / 4; ++d4) {
      float4 u4 = *reinterpret_cast<const float4*>(&upd[s][d4 * 4]);
      float4 p4 = *reinterpret_cast<const float4*>(&sprev[s][d4 * 4]);
      float4 wi4 = *reinterpret_cast<const float4*>(wi + d4 * 4);
      float4 wh4 = *reinterpret_cast<const float4*>(wh + d4 * 4);
      ax += u4.x * wi4.x + u4.y * wi4.y + u4.z * wi4.z + u4.w * wi4.w;
      ah += p4.x * wh4.x + p4.y * wh4.y + p4.z * wh4.z + p4.w * wh4.w;
    }
    gxs[s][e] = ax + b_ih[e];
    ghs[s][e] = ah + b_hh[e];
  }
  __syncthreads();

  {  // gates
    int s = t >> 5, c = t & 31;
#pragma unroll
    for (int ii = 0; ii < 4; ++ii) {
      int d = c + 32 * ii;
      float xr = gxs[s][d], xz = gxs[s][DIM + d], xn = gxs[s][2 * DIM + d];
      float hr = ghs[s][d], hz = ghs[s][DIM + d], hn = ghs[s][2 * DIM + d];
      float r = 1.0f / (1.0f + expf(-(xr + hr)));
      float z = 1.0f / (1.0f + expf(-(xz + hz)));
      float ng = tanhf(xn + r * hn);
      snew[s][d] = (1.0f - z) * ng + z * sprev[s][d];
    }
  }
  __syncthreads();

  {  // LN(snew) -> ffin
    int s = t >> 5, c = t & 31;
    float4 xv = *reinterpret_cast<const float4*>(&snew[s][c * 4]);
    float ps = xv.x + xv.y + xv.z + xv.w;
    float pq = xv.x * xv.x + xv.y * xv.y + xv.z * xv.z + xv.w * xv.w;
#pragma unroll
    for (int m = 16; m >= 1; m >>= 1) {
      ps += __shfl_xor(ps, m, 32);
      pq += __shfl_xor(pq, m, 32);
    }
    float mean = ps * (1.0f / DIM);
    float var = fmaxf(pq * (1.0f / DIM) - mean * mean, 0.0f);
    float inv = 1.0f / sqrtf(var + LN_EPS);
    float vals[4] = {xv.x, xv.y, xv.z, xv.w};
#pragma unroll
    for (int ii = 0; ii < 4; ++ii) {
      int d = c * 4 + ii;
      ffin[s][d] = (vals[ii] - mean) * inv * lnfw[d] + lnfb[d];
    }
  }
  __syncthreads();

  {  // ff = relu(ffin @ W1^T + b1)
    int s = t >> 5, c = t & 31;
#pragma unroll
    for (int ii = 0; ii < 4; ++ii) {
      int e = c + 32 * ii;
      const float* w = W1 + e * DIM;
      float acc = 0.0f;
#pragma unroll
      for (int d4 = 0; d4 < DIM / 4; ++d4) {
        float4 f4 = *reinterpret_cast<const float4*>(&ffin[s][d4 * 4]);
        float4 w4 = *reinterpret_cast<const float4*>(w + d4 * 4);
        acc += f4.x * w4.x + f4.y * w4.y + f4.z * w4.z + f4.w * w4.w;
      }
      ffb[s][e] = fmaxf(acc + b1[e], 0.0f);
    }
  }
  __syncthreads();

  {  // slots = snew + ffb @ W2^T + b2
    int s = t >> 5, c = t & 31;
#pragma unroll
    for (int ii = 0; ii < 4; ++ii) {
      int d = c + 32 * ii;
      const float* w = W2 + d * DIM;
      float acc = 0.0f;
#pragma unroll
      for (int h4 = 0; h4 < DIM / 4; ++h4) {
        float4 f4 = *reinterpret_cast<const float4*>(&ffb[s][h4 * 4]);
        float4 w4 = *reinterpret_cast<const float4*>(w + h4 * 4);
        acc += f4.x * w4.x + f4.y * w4.y + f4.z * w4.z + f4.w * w4.w;
      }
      sl[s * DIM + d] = snew[s][d] + acc + b2[d];
    }
  }
}

__global__ __launch_bounds__(256) void k_sentinel(float* __restrict__ out,
                                                  int n) {
  int i = blockIdx.x * blockDim.x + threadIdx.x;
  if (i < n) out[i] = 1234.5f;
}

// ---------------------------------------------------------------------------
extern "C" void kernel_launch(void* const* d_in, const int* in_sizes, int n_in,
                              void* d_out, int out_size, void* d_ws,
                              size_t ws_size, hipStream_t stream) {
  const float* inp = (const float*)d_in[0];
  const float* mu = (const float*)d_in[1];
  const float* lsig = (const float*)d_in[2];
  const float* Wq = (const float*)d_in[3];
  const float* Wk = (const float*)d_in[4];
  const float* Wv = (const float*)d_in[5];
  const float* W_ih = (const float*)d_in[6];
  const float* W_hh = (const float*)d_in[7];
  const float* b_ih = (const float*)d_in[8];
  const float* b_hh = (const float*)d_in[9];
  const float* W1 = (const float*)d_in[10];
  const float* b1 = (const float*)d_in[11];
  const float* W2 = (const float*)d_in[12];
  const float* b2 = (const float*)d_in[13];
  const float* ln_in_w = (const float*)d_in[14];
  const float* ln_in_b = (const float*)d_in[15];
  const float* ln_s_w = (const float*)d_in[16];
  const float* ln_s_b = (const float*)d_in[17];
  const float* ln_ff_w = (const float*)d_in[18];
  const float* ln_ff_b = (const float*)d_in[19];

  float* slots = (float*)d_out;

  // ws layout: q (f32) | kt (bf16) | vt (bf16) | Np (f32) | Dp (f32)
  const size_t q_elems = (size_t)NB * NSLOT * DIM;
  const size_t kv_elems = (size_t)NB * DIM * NTOK;
  const size_t np_elems = (size_t)NB * NCH * NSLOT * DIM;
  const size_t dp_elems = (size_t)NB * NCH * NSLOT;
  size_t need = q_elems * 4 + kv_elems * 2 * 2 + np_elems * 4 + dp_elems * 4;
  if (ws_size < need) {
    k_sentinel<<<(out_size + 255) / 256, 256, 0, stream>>>((float*)d_out,
                                                           out_size);
    return;
  }
  char* wsb = (char*)d_ws;
  float* q = (float*)wsb;
  unsigned short* kt = (unsigned short*)(wsb + q_elems * 4);
  unsigned short* vt = kt + kv_elems;
  float* Np = (float*)(wsb + q_elems * 4 + kv_elems * 4);
  float* Dp = Np + np_elems;

  k_init_slots<<<(NB * NSLOT * DIM) / 256, 256, 0, stream>>>(mu, lsig, slots);
  k_ln_kv<<<(NB * NTOK) / 256, 256, 0, stream>>>(inp, Wk, Wv, ln_in_w, ln_in_b,
                                                 kt, vt);
  for (int it = 0; it < 3; ++it) {
    k_qproj<<<NB, 256, 0, stream>>>(slots, Wq, ln_s_w, ln_s_b, q);
    k_attn<<<NB * NCH, 256, 0, stream>>>(q, kt, vt, Np, Dp);
    k_update<<<NB, 256, 0, stream>>>(slots, Np, Dp, W_ih, W_hh, b_ih, b_hh, W1,
                                     b1, W2, b2, ln_ff_w, ln_ff_b);
  }
}

// Round 3
// 340.743 us; speedup vs baseline: 2.4226x; 2.4226x over previous
//
#include <hip/hip_runtime.h>
#include <hip/hip_bf16.h>
#include <math.h>

#define DIM 128
#define NSLOT 8
#define NTOK 4096
#define NB 32
#define CHUNK 128
#define NCH (NTOK / CHUNK)   // 32
#define LN_EPS 1e-3f
#define ATT_EPS 1e-8f
#define SCALE 0.08838834764831845f  // 128^-0.5

#define BM 64     // tokens per GEMM block
#define LDK 136   // padded LDS row length in bf16 elems (272 B, 16B-aligned)

typedef short bf16x8 __attribute__((ext_vector_type(8)));
typedef float f32x4 __attribute__((ext_vector_type(4)));
typedef unsigned short ushort8_t __attribute__((ext_vector_type(8)));

__device__ __forceinline__ float bf2f(unsigned short u) {
  return __uint_as_float(((unsigned)u) << 16);
}
__device__ __forceinline__ unsigned short f2bf(float f) {
  unsigned u = __float_as_uint(f);
  unsigned r = (u + 0x7FFFu + ((u >> 16) & 1u)) >> 16;
  return (unsigned short)r;
}

// ---------------------------------------------------------------------------
// Kernel 1: partitionable-threefry normal(key(42)) -> slots init
// ---------------------------------------------------------------------------
__device__ __forceinline__ float erfinv_like_xla(float x) {
  double xd = (double)x;
  double w = -log1p(-xd * xd);
  double p;
  if (w < 5.0) {
    w = w - 2.5;
    p = 2.81022636e-08;
    p = 3.43273939e-07 + p * w;
    p = -3.5233877e-06 + p * w;
    p = -4.39150654e-06 + p * w;
    p = 0.00021858087 + p * w;
    p = -0.00125372503 + p * w;
    p = -0.00417768164 + p * w;
    p = 0.246640727 + p * w;
    p = 1.50140941 + p * w;
  } else {
    w = sqrt(w) - 3.0;
    p = -0.000200214257;
    p = 0.000100950558 + p * w;
    p = 0.00134934322 + p * w;
    p = -0.00367342844 + p * w;
    p = 0.00573950773 + p * w;
    p = -0.0076224613 + p * w;
    p = 0.00943887047 + p * w;
    p = 1.00167406 + p * w;
    p = 2.83297682 + p * w;
  }
  return (float)(p * xd);
}

__global__ __launch_bounds__(256) void k_init_slots(
    const float* __restrict__ mu, const float* __restrict__ lsig,
    float* __restrict__ slots) {
  int t = blockIdx.x * blockDim.x + threadIdx.x;
  if (t >= NB * NSLOT * DIM) return;
  uint32_t x0 = 0u, x1 = (uint32_t)t;
  uint32_t k0 = 0u, k1 = 42u;
  uint32_t ks[3] = {k0, k1, k0 ^ k1 ^ 0x1BD11BDAu};
  x0 += ks[0];
  x1 += ks[1];
  const int rot[2][4] = {{13, 15, 26, 6}, {17, 29, 16, 24}};
#pragma unroll
  for (int blk = 0; blk < 5; ++blk) {
    const int* r = rot[blk & 1];
#pragma unroll
    for (int j = 0; j < 4; ++j) {
      x0 += x1;
      x1 = (x1 << r[j]) | (x1 >> (32 - r[j]));
      x1 ^= x0;
    }
    x0 += ks[(blk + 1) % 3];
    x1 += ks[(blk + 2) % 3] + (uint32_t)(blk + 1);
  }
  uint32_t bits = x0 ^ x1;
  float f = __uint_as_float((bits >> 9) | 0x3F800000u) - 1.0f;
  const float mn = __uint_as_float(0xBF7FFFFFu);
  float u = fmaxf(f * 2.0f + mn, mn);
  float noise = 1.41421356f * erfinv_like_xla(u);
  int d = t & (DIM - 1);
  slots[t] = mu[d] + expf(lsig[d]) * noise;
}

// ---------------------------------------------------------------------------
// Kernel 1b: cast Wk, Wv to bf16 into ws (one-time)
// ---------------------------------------------------------------------------
__global__ __launch_bounds__(256) void k_wcast(const float* __restrict__ Wk,
                                               const float* __restrict__ Wv,
                                               unsigned short* __restrict__ Wbf) {
  int i = blockIdx.x * 256 + threadIdx.x;  // < 16384
  if (i >= DIM * DIM) return;
  Wbf[i] = f2bf(Wk[i]);
  Wbf[DIM * DIM + i] = f2bf(Wv[i]);
}

// ---------------------------------------------------------------------------
// Kernel 2: LN + MFMA projection. Block: BM=64 tokens x 128 outputs of one
// matrix (grid.y: 0=kt, 1=vt). Output transposed [b][e][n] bf16.
// ---------------------------------------------------------------------------
__global__ __launch_bounds__(256) void k_ln_kv_mfma(
    const float* __restrict__ inp, const unsigned short* __restrict__ Wbf,
    const float* __restrict__ lnw, const float* __restrict__ lnb,
    unsigned short* __restrict__ kt, unsigned short* __restrict__ vt) {
  __shared__ unsigned short x_lds[BM][LDK];   // 17408 B
  __shared__ unsigned short w_lds[DIM][LDK];  // 34816 B
  int t = threadIdx.x;
  int tg = blockIdx.x;   // token group (64 tokens)
  int mat = blockIdx.y;  // 0 = kt, 1 = vt

  {  // Phase A: LN 64 rows -> bf16 LDS. thread = (row r, quarter qh)
    int r = t >> 2, qh = t & 3;
    const float* src = inp + ((size_t)tg * BM + r) * DIM + qh * 32;
    float xr[32];
    float s = 0.f, sq = 0.f;
#pragma unroll
    for (int i4 = 0; i4 < 8; ++i4) {
      float4 v = *reinterpret_cast<const float4*>(src + i4 * 4);
      xr[i4 * 4 + 0] = v.x; xr[i4 * 4 + 1] = v.y;
      xr[i4 * 4 + 2] = v.z; xr[i4 * 4 + 3] = v.w;
      s += v.x + v.y + v.z + v.w;
      sq += v.x * v.x + v.y * v.y + v.z * v.z + v.w * v.w;
    }
    s += __shfl_xor(s, 1); sq += __shfl_xor(sq, 1);
    s += __shfl_xor(s, 2); sq += __shfl_xor(sq, 2);
    float mean = s * (1.0f / DIM);
    float var = fmaxf(sq * (1.0f / DIM) - mean * mean, 0.0f);
    float inv = 1.0f / sqrtf(var + LN_EPS);
#pragma unroll
    for (int c8 = 0; c8 < 4; ++c8) {
      ushort8_t pk;
#pragma unroll
      for (int j = 0; j < 8; ++j) {
        int d = qh * 32 + c8 * 8 + j;
        float y = (xr[c8 * 8 + j] - mean) * inv * lnw[d] + lnb[d];
        pk[j] = f2bf(y);
      }
      *reinterpret_cast<ushort8_t*>(&x_lds[r][qh * 32 + c8 * 8]) = pk;
    }
  }
  {  // Phase B: stage W[e][d] bf16. thread = (row r, half h)
    int r = t >> 1, h = t & 1;
    const unsigned short* wsrc = Wbf + mat * DIM * DIM + r * DIM + h * 64;
#pragma unroll
    for (int c8 = 0; c8 < 8; ++c8) {
      *reinterpret_cast<ushort8_t*>(&w_lds[r][h * 64 + c8 * 8]) =
          *reinterpret_cast<const ushort8_t*>(wsrc + c8 * 8);
    }
  }
  __syncthreads();

  // Phase C: MFMA. wave w: e in [w*32, w*32+32), all 64 tokens.
  int w = t >> 6, l = t & 63;
  int lm = l & 15, lg = l >> 4;
  f32x4 acc[2][4];
#pragma unroll
  for (int et = 0; et < 2; ++et)
#pragma unroll
    for (int tt = 0; tt < 4; ++tt) acc[et][tt] = (f32x4){0.f, 0.f, 0.f, 0.f};

#pragma unroll
  for (int ks = 0; ks < 4; ++ks) {
    int k0 = ks * 32;
    bf16x8 af[2], bfr[4];
#pragma unroll
    for (int et = 0; et < 2; ++et)
      af[et] = *reinterpret_cast<const bf16x8*>(
          &w_lds[w * 32 + et * 16 + lm][k0 + 8 * lg]);
#pragma unroll
    for (int tt = 0; tt < 4; ++tt)
      bfr[tt] = *reinterpret_cast<const bf16x8*>(
          &x_lds[tt * 16 + lm][k0 + 8 * lg]);
#pragma unroll
    for (int et = 0; et < 2; ++et)
#pragma unroll
      for (int tt = 0; tt < 4; ++tt)
        acc[et][tt] = __builtin_amdgcn_mfma_f32_16x16x32_bf16(
            af[et], bfr[tt], acc[et][tt], 0, 0, 0);
  }

  // Phase D: store. D: row=e-offset 4*lg+reg, col=token lm.
  unsigned short* dst = mat ? vt : kt;
  size_t gtok0 = (size_t)tg * BM;
  int b = (int)(gtok0 >> 12);
  int n0b = (int)(gtok0 & (NTOK - 1));
#pragma unroll
  for (int et = 0; et < 2; ++et)
#pragma unroll
    for (int tt = 0; tt < 4; ++tt)
#pragma unroll
      for (int r = 0; r < 4; ++r) {
        int e = w * 32 + et * 16 + lg * 4 + r;
        int n = tt * 16 + lm;
        dst[(size_t)b * DIM * NTOK + (size_t)e * NTOK + n0b + n] =
            f2bf(acc[et][tt][r]);
      }
}

// ---------------------------------------------------------------------------
// Kernel 3: q = LN(slots) @ Wq^T
// ---------------------------------------------------------------------------
__global__ __launch_bounds__(256) void k_qproj(
    const float* __restrict__ slots, const float* __restrict__ Wq,
    const float* __restrict__ lnw, const float* __restrict__ lnb,
    float* __restrict__ q) {
  int b = blockIdx.x, t = threadIdx.x;
  int s = t >> 5, c = t & 31;
  __shared__ __align__(16) float sln[NSLOT][DIM];
  const float* sb = slots + (b * NSLOT + s) * DIM;
  float4 xv = *reinterpret_cast<const float4*>(sb + c * 4);
  float ps = xv.x + xv.y + xv.z + xv.w;
  float pq = xv.x * xv.x + xv.y * xv.y + xv.z * xv.z + xv.w * xv.w;
#pragma unroll
  for (int m = 16; m >= 1; m >>= 1) {
    ps += __shfl_xor(ps, m, 32);
    pq += __shfl_xor(pq, m, 32);
  }
  float mean = ps * (1.0f / DIM);
  float var = fmaxf(pq * (1.0f / DIM) - mean * mean, 0.0f);
  float inv = 1.0f / sqrtf(var + LN_EPS);
  float vals[4] = {xv.x, xv.y, xv.z, xv.w};
#pragma unroll
  for (int ii = 0; ii < 4; ++ii) {
    int d = c * 4 + ii;
    sln[s][d] = (vals[ii] - mean) * inv * lnw[d] + lnb[d];
  }
  __syncthreads();
#pragma unroll
  for (int ii = 0; ii < 4; ++ii) {
    int e = c + 32 * ii;
    const float* w = Wq + e * DIM;
    float acc = 0.0f;
#pragma unroll
    for (int d4 = 0; d4 < DIM / 4; ++d4) {
      float4 w4 = *reinterpret_cast<const float4*>(w + d4 * 4);
      float4 s4 = *reinterpret_cast<const float4*>(&sln[s][d4 * 4]);
      acc += s4.x * w4.x + s4.y * w4.y + s4.z * w4.z + s4.w * w4.w;
    }
    q[(b * NSLOT + s) * DIM + e] = acc;
  }
}

// ---------------------------------------------------------------------------
// Kernel 4: per (batch, 128-token chunk): dots -> softmax over slots -> +eps
// -> partial D and N sums.
// ---------------------------------------------------------------------------
__global__ __launch_bounds__(256) void k_attn(
    const float* __restrict__ q, const unsigned short* __restrict__ kt,
    const unsigned short* __restrict__ vt, float* __restrict__ Np,
    float* __restrict__ Dp) {
  int bid = blockIdx.x;
  int b = bid >> 5, ch = bid & 31;
  int tok0 = ch * CHUNK;
  int t = threadIdx.x;
  __shared__ __align__(16) float a_t[CHUNK][NSLOT];

  {  // phase 1: 2 threads per token (d halves), shuffle-combine
    int j = t >> 1, h = t & 1;
    const unsigned short* kb = kt + (size_t)b * DIM * NTOK + tok0 + j;
    const float* qb = q + b * NSLOT * DIM + h * 64;
    float dots[NSLOT];
#pragma unroll
    for (int i = 0; i < NSLOT; ++i) dots[i] = 0.0f;
    for (int dd = 0; dd < 64; ++dd) {
      float kv = bf2f(kb[(size_t)(h * 64 + dd) * NTOK]);
#pragma unroll
      for (int i = 0; i < NSLOT; ++i) dots[i] += qb[i * DIM + dd] * kv;
    }
#pragma unroll
    for (int i = 0; i < NSLOT; ++i) dots[i] += __shfl_xor(dots[i], 1);
    if (h == 0) {
      float m = -1e30f;
#pragma unroll
      for (int i = 0; i < NSLOT; ++i) {
        dots[i] *= SCALE;
        m = fmaxf(m, dots[i]);
      }
      float ssum = 0.0f;
#pragma unroll
      for (int i = 0; i < NSLOT; ++i) {
        dots[i] = expf(dots[i] - m);
        ssum += dots[i];
      }
      float rs = 1.0f / ssum;
#pragma unroll
      for (int i = 0; i < NSLOT; ++i) a_t[j][i] = dots[i] * rs + ATT_EPS;
    }
  }
  __syncthreads();

  {  // phase 2a: D partials
    int i = t >> 5, c = t & 31;
    float s = 0.0f;
#pragma unroll
    for (int jj = 0; jj < CHUNK / 32; ++jj) s += a_t[c + 32 * jj][i];
#pragma unroll
    for (int m = 16; m >= 1; m >>= 1) s += __shfl_xor(s, m, 32);
    if (c == 0) Dp[(b * NCH + ch) * NSLOT + i] = s;
  }

  {  // phase 2b: N partials; thread owns (d, group of 4 slots)
    int d = t & (DIM - 1), ig = t >> 7;
    const unsigned short* vb = vt + (size_t)(b * DIM + d) * NTOK + tok0;
    float acc0 = 0, acc1 = 0, acc2 = 0, acc3 = 0;
    for (int j4 = 0; j4 < CHUNK / 4; ++j4) {
      ushort4 vv = *reinterpret_cast<const ushort4*>(vb + j4 * 4);
      float vvals[4] = {bf2f(vv.x), bf2f(vv.y), bf2f(vv.z), bf2f(vv.w)};
#pragma unroll
      for (int u = 0; u < 4; ++u) {
        float4 av =
            *reinterpret_cast<const float4*>(&a_t[j4 * 4 + u][ig * 4]);
        acc0 += vvals[u] * av.x;
        acc1 += vvals[u] * av.y;
        acc2 += vvals[u] * av.z;
        acc3 += vvals[u] * av.w;
      }
    }
    size_t base = (size_t)(b * NCH + ch) * NSLOT;
    Np[(base + ig * 4 + 0) * DIM + d] = acc0;
    Np[(base + ig * 4 + 1) * DIM + d] = acc1;
    Np[(base + ig * 4 + 2) * DIM + d] = acc2;
    Np[(base + ig * 4 + 3) * DIM + d] = acc3;
  }
}

// ---------------------------------------------------------------------------
// Kernel 5: per (batch, slot) block: reduce partials -> update -> GRU -> MLP
// ---------------------------------------------------------------------------
__global__ __launch_bounds__(256) void k_update(
    float* __restrict__ slots, const float* __restrict__ Np,
    const float* __restrict__ Dp, const float* __restrict__ W_ih,
    const float* __restrict__ W_hh, const float* __restrict__ b_ih,
    const float* __restrict__ b_hh, const float* __restrict__ W1,
    const float* __restrict__ b1, const float* __restrict__ W2,
    const float* __restrict__ b2, const float* __restrict__ lnfw,
    const float* __restrict__ lnfb) {
  int bs = blockIdx.x;
  int b = bs >> 3, s = bs & 7;
  int t = threadIdx.x;
  __shared__ __align__(16) float upd[DIM];
  __shared__ __align__(16) float sprev[DIM];
  __shared__ __align__(16) float snew[DIM];
  __shared__ __align__(16) float ffin[DIM];
  __shared__ __align__(16) float ffb[DIM];
  __shared__ __align__(16) float gx[3 * DIM];
  __shared__ __align__(16) float gh[3 * DIM];

  float dsum = 0.0f;  // block-uniform (scalar loads)
  for (int ch = 0; ch < NCH; ++ch) dsum += Dp[(b * NCH + ch) * NSLOT + s];

  if (t < DIM) {
    sprev[t] = slots[(b * NSLOT + s) * DIM + t];
    float a = 0.0f;
    for (int ch = 0; ch < NCH; ++ch)
      a += Np[((size_t)(b * NCH + ch) * NSLOT + s) * DIM + t];
    upd[t] = a / dsum;
  }
  __syncthreads();

  for (int e = t; e < 3 * DIM; e += 256) {
    const float* wi = W_ih + e * DIM;
    const float* wh = W_hh + e * DIM;
    float ax = 0.0f, ah = 0.0f;
#pragma unroll
    for (int d4 = 0; d4 < DIM / 4; ++d4) {
      float4 u4 = *reinterpret_cast<const float4*>(&upd[d4 * 4]);
      float4 p4 = *reinterpret_cast<const float4*>(&sprev[d4 * 4]);
      float4 wi4 = *reinterpret_cast<const float4*>(wi + d4 * 4);
      float4 wh4 = *reinterpret_cast<const float4*>(wh + d4 * 4);
      ax += u4.x * wi4.x + u4.y * wi4.y + u4.z * wi4.z + u4.w * wi4.w;
      ah += p4.x * wh4.x + p4.y * wh4.y + p4.z * wh4.z + p4.w * wh4.w;
    }
    gx[e] = ax + b_ih[e];
    gh[e] = ah + b_hh[e];
  }
  __syncthreads();

  if (t < DIM) {
    float xr = gx[t], xz = gx[DIM + t], xn = gx[2 * DIM + t];
    float hr = gh[t], hz = gh[DIM + t], hn = gh[2 * DIM + t];
    float r = 1.0f / (1.0f + expf(-(xr + hr)));
    float z = 1.0f / (1.0f + expf(-(xz + hz)));
    float ng = tanhf(xn + r * hn);
    snew[t] = (1.0f - z) * ng + z * sprev[t];
  }
  __syncthreads();

  if (t < DIM) {  // LN(snew): serial broadcast reduce (128 iters, LDS-hot)
    float s1 = 0.0f, s2 = 0.0f;
#pragma unroll 8
    for (int d = 0; d < DIM; ++d) {
      float v = snew[d];
      s1 += v;
      s2 += v * v;
    }
    float mean = s1 * (1.0f / DIM);
    float var = fmaxf(s2 * (1.0f / DIM) - mean * mean, 0.0f);
    float inv = 1.0f / sqrtf(var + LN_EPS);
    ffin[t] = (snew[t] - mean) * inv * lnfw[t] + lnfb[t];
  }
  __syncthreads();

  if (t < DIM) {  // ff = relu(ffin @ W1^T + b1)
    const float* w = W1 + t * DIM;
    float acc = 0.0f;
#pragma unroll
    for (int d4 = 0; d4 < DIM / 4; ++d4) {
      float4 f4 = *reinterpret_cast<const float4*>(&ffin[d4 * 4]);
      float4 w4 = *reinterpret_cast<const float4*>(w + d4 * 4);
      acc += f4.x * w4.x + f4.y * w4.y + f4.z * w4.z + f4.w * w4.w;
    }
    ffb[t] = fmaxf(acc + b1[t], 0.0f);
  }
  __syncthreads();

  if (t < DIM) {  // out = snew + ffb @ W2^T + b2
    const float* w = W2 + t * DIM;
    float acc = 0.0f;
#pragma unroll
    for (int h4 = 0; h4 < DIM / 4; ++h4) {
      float4 f4 = *reinterpret_cast<const float4*>(&ffb[h4 * 4]);
      float4 w4 = *reinterpret_cast<const float4*>(w + h4 * 4);
      acc += f4.x * w4.x + f4.y * w4.y + f4.z * w4.z + f4.w * w4.w;
    }
    slots[(b * NSLOT + s) * DIM + t] = snew[t] + acc + b2[t];
  }
}

__global__ __launch_bounds__(256) void k_sentinel(float* __restrict__ out,
                                                  int n) {
  int i = blockIdx.x * blockDim.x + threadIdx.x;
  if (i < n) out[i] = 1234.5f;
}

// ---------------------------------------------------------------------------
extern "C" void kernel_launch(void* const* d_in, const int* in_sizes, int n_in,
                              void* d_out, int out_size, void* d_ws,
                              size_t ws_size, hipStream_t stream) {
  const float* inp = (const float*)d_in[0];
  const float* mu = (const float*)d_in[1];
  const float* lsig = (const float*)d_in[2];
  const float* Wq = (const float*)d_in[3];
  const float* Wk = (const float*)d_in[4];
  const float* Wv = (const float*)d_in[5];
  const float* W_ih = (const float*)d_in[6];
  const float* W_hh = (const float*)d_in[7];
  const float* b_ih = (const float*)d_in[8];
  const float* b_hh = (const float*)d_in[9];
  const float* W1 = (const float*)d_in[10];
  const float* b1 = (const float*)d_in[11];
  const float* W2 = (const float*)d_in[12];
  const float* b2 = (const float*)d_in[13];
  const float* ln_in_w = (const float*)d_in[14];
  const float* ln_in_b = (const float*)d_in[15];
  const float* ln_s_w = (const float*)d_in[16];
  const float* ln_s_b = (const float*)d_in[17];
  const float* ln_ff_w = (const float*)d_in[18];
  const float* ln_ff_b = (const float*)d_in[19];

  float* slots = (float*)d_out;

  // ws layout: q f32 | kt bf16 | vt bf16 | Wbf bf16 | Np f32 | Dp f32
  const size_t q_elems = (size_t)NB * NSLOT * DIM;
  const size_t kv_elems = (size_t)NB * DIM * NTOK;
  const size_t w_elems = (size_t)2 * DIM * DIM;
  const size_t np_elems = (size_t)NB * NCH * NSLOT * DIM;
  const size_t dp_elems = (size_t)NB * NCH * NSLOT;
  size_t need = q_elems * 4 + kv_elems * 2 * 2 + w_elems * 2 + np_elems * 4 +
                dp_elems * 4;
  if (ws_size < need) {
    k_sentinel<<<(out_size + 255) / 256, 256, 0, stream>>>((float*)d_out,
                                                           out_size);
    return;
  }
  char* wsb = (char*)d_ws;
  float* q = (float*)wsb;
  unsigned short* kt = (unsigned short*)(wsb + q_elems * 4);
  unsigned short* vt = kt + kv_elems;
  unsigned short* Wbf = vt + kv_elems;
  float* Np = (float*)(wsb + q_elems * 4 + kv_elems * 4 + w_elems * 2);
  float* Dp = Np + np_elems;

  k_init_slots<<<(NB * NSLOT * DIM) / 256, 256, 0, stream>>>(mu, lsig, slots);
  k_wcast<<<(DIM * DIM) / 256, 256, 0, stream>>>(Wk, Wv, Wbf);
  k_ln_kv_mfma<<<dim3(NB * NTOK / BM, 2), 256, 0, stream>>>(
      inp, Wbf, ln_in_w, ln_in_b, kt, vt);
  for (int it = 0; it < 3; ++it) {
    k_qproj<<<NB, 256, 0, stream>>>(slots, Wq, ln_s_w, ln_s_b, q);
    k_attn<<<NB * NCH, 256, 0, stream>>>(q, kt, vt, Np, Dp);
    k_update<<<NB * NSLOT, 256, 0, stream>>>(slots, Np, Dp, W_ih, W_hh, b_ih,
                                             b_hh, W1, b1, W2, b2, ln_ff_w,
                                             ln_ff_b);
  }
}

// Round 4
// 223.331 us; speedup vs baseline: 3.6962x; 1.5257x over previous
//
#include <hip/hip_runtime.h>
#include <hip/hip_bf16.h>
#include <math.h>

#define DIM 128
#define NSLOT 8
#define NTOK 4096
#define NB 32
#define CHUNK 512
#define NCH (NTOK / CHUNK)   // 8
#define LN_EPS 1e-3f
#define ATT_EPS 1e-8f
#define SCALE 0.08838834764831845f  // 128^-0.5

#define BM 64     // tokens per GEMM block
#define LDK 136   // padded LDS row length in bf16 elems (272 B)

typedef short bf16x8 __attribute__((ext_vector_type(8)));
typedef float f32x4 __attribute__((ext_vector_type(4)));
typedef unsigned short ushort8_t __attribute__((ext_vector_type(8)));

__device__ __forceinline__ float bf2f(unsigned short u) {
  return __uint_as_float(((unsigned)u) << 16);
}
__device__ __forceinline__ unsigned short f2bf(float f) {
  unsigned u = __float_as_uint(f);
  unsigned r = (u + 0x7FFFu + ((u >> 16) & 1u)) >> 16;
  return (unsigned short)r;
}

// ---------------------------------------------------------------------------
// Kernel 1: partitionable-threefry normal(key(42)) -> slots init
// ---------------------------------------------------------------------------
__device__ __forceinline__ float erfinv_like_xla(float x) {
  double xd = (double)x;
  double w = -log1p(-xd * xd);
  double p;
  if (w < 5.0) {
    w = w - 2.5;
    p = 2.81022636e-08;
    p = 3.43273939e-07 + p * w;
    p = -3.5233877e-06 + p * w;
    p = -4.39150654e-06 + p * w;
    p = 0.00021858087 + p * w;
    p = -0.00125372503 + p * w;
    p = -0.00417768164 + p * w;
    p = 0.246640727 + p * w;
    p = 1.50140941 + p * w;
  } else {
    w = sqrt(w) - 3.0;
    p = -0.000200214257;
    p = 0.000100950558 + p * w;
    p = 0.00134934322 + p * w;
    p = -0.00367342844 + p * w;
    p = 0.00573950773 + p * w;
    p = -0.0076224613 + p * w;
    p = 0.00943887047 + p * w;
    p = 1.00167406 + p * w;
    p = 2.83297682 + p * w;
  }
  return (float)(p * xd);
}

__global__ __launch_bounds__(256) void k_init_slots(
    const float* __restrict__ mu, const float* __restrict__ lsig,
    float* __restrict__ slots) {
  int t = blockIdx.x * blockDim.x + threadIdx.x;
  if (t >= NB * NSLOT * DIM) return;
  uint32_t x0 = 0u, x1 = (uint32_t)t;
  uint32_t k0 = 0u, k1 = 42u;
  uint32_t ks[3] = {k0, k1, k0 ^ k1 ^ 0x1BD11BDAu};
  x0 += ks[0];
  x1 += ks[1];
  const int rot[2][4] = {{13, 15, 26, 6}, {17, 29, 16, 24}};
#pragma unroll
  for (int blk = 0; blk < 5; ++blk) {
    const int* r = rot[blk & 1];
#pragma unroll
    for (int j = 0; j < 4; ++j) {
      x0 += x1;
      x1 = (x1 << r[j]) | (x1 >> (32 - r[j]));
      x1 ^= x0;
    }
    x0 += ks[(blk + 1) % 3];
    x1 += ks[(blk + 2) % 3] + (uint32_t)(blk + 1);
  }
  uint32_t bits = x0 ^ x1;
  float f = __uint_as_float((bits >> 9) | 0x3F800000u) - 1.0f;
  const float mn = __uint_as_float(0xBF7FFFFFu);
  float u = fmaxf(f * 2.0f + mn, mn);
  float noise = 1.41421356f * erfinv_like_xla(u);
  int d = t & (DIM - 1);
  slots[t] = mu[d] + expf(lsig[d]) * noise;
}

// ---------------------------------------------------------------------------
// Kernel 1b: cast Wk, Wv to bf16 into ws (one-time)
// ---------------------------------------------------------------------------
__global__ __launch_bounds__(256) void k_wcast(const float* __restrict__ Wk,
                                               const float* __restrict__ Wv,
                                               unsigned short* __restrict__ Wbf) {
  int i = blockIdx.x * 256 + threadIdx.x;
  if (i >= DIM * DIM) return;
  Wbf[i] = f2bf(Wk[i]);
  Wbf[DIM * DIM + i] = f2bf(Wv[i]);
}

// ---------------------------------------------------------------------------
// Kernel 2: LN + MFMA projection, one pass. Block = 64 tokens, 4 waves:
//   wave 0,1: kt e[0..63],[64..127], layout [b][n][d]  (A=x, B=Wk)
//   wave 2,3: vt e[0..63],[64..127], layout [b][d][n]  (A=Wv, B=x)
// W fragments from global (L2-hot). LDS only holds LN'd x (bf16).
// ---------------------------------------------------------------------------
__global__ __launch_bounds__(256) void k_ln_kv(
    const float* __restrict__ inp, const unsigned short* __restrict__ Wbf,
    const float* __restrict__ lnw, const float* __restrict__ lnb,
    unsigned short* __restrict__ kt, unsigned short* __restrict__ vt) {
  __shared__ unsigned short x_lds[BM][LDK];  // 17408 B
  int t = threadIdx.x;
  int tg = blockIdx.x;  // token group (64 tokens)

  {  // Phase A: LN 64 rows -> bf16 LDS. thread = (row r, quarter qh)
    int r = t >> 2, qh = t & 3;
    const float* src = inp + ((size_t)tg * BM + r) * DIM + qh * 32;
    float xr[32];
    float s = 0.f, sq = 0.f;
#pragma unroll
    for (int i4 = 0; i4 < 8; ++i4) {
      float4 v = *reinterpret_cast<const float4*>(src + i4 * 4);
      xr[i4 * 4 + 0] = v.x; xr[i4 * 4 + 1] = v.y;
      xr[i4 * 4 + 2] = v.z; xr[i4 * 4 + 3] = v.w;
      s += v.x + v.y + v.z + v.w;
      sq += v.x * v.x + v.y * v.y + v.z * v.z + v.w * v.w;
    }
    s += __shfl_xor(s, 1); sq += __shfl_xor(sq, 1);
    s += __shfl_xor(s, 2); sq += __shfl_xor(sq, 2);
    float mean = s * (1.0f / DIM);
    float var = fmaxf(sq * (1.0f / DIM) - mean * mean, 0.0f);
    float inv = 1.0f / sqrtf(var + LN_EPS);
#pragma unroll
    for (int c8 = 0; c8 < 4; ++c8) {
      ushort8_t pk;
#pragma unroll
      for (int j = 0; j < 8; ++j) {
        int d = qh * 32 + c8 * 8 + j;
        float y = (xr[c8 * 8 + j] - mean) * inv * lnw[d] + lnb[d];
        pk[j] = f2bf(y);
      }
      *reinterpret_cast<ushort8_t*>(&x_lds[r][qh * 32 + c8 * 8]) = pk;
    }
  }
  __syncthreads();

  int w = t >> 6, l = t & 63, lm = l & 15, lg = l >> 4;
  int mat = w >> 1;          // 0: kt, 1: vt
  int ebase = (w & 1) * 64;  // 64 e's per wave
  const unsigned short* Wsrc = Wbf + mat * DIM * DIM;

  f32x4 acc[4][4];
#pragma unroll
  for (int i = 0; i < 4; ++i)
#pragma unroll
    for (int j = 0; j < 4; ++j) acc[i][j] = (f32x4){0.f, 0.f, 0.f, 0.f};

  if (mat == 0) {  // kt: acc[tt][et], rows = tokens, cols = e
#pragma unroll
    for (int ks = 0; ks < 4; ++ks) {
      bf16x8 wf[4], xf[4];
#pragma unroll
      for (int et = 0; et < 4; ++et)
        wf[et] = *reinterpret_cast<const bf16x8*>(
            Wsrc + (ebase + et * 16 + lm) * DIM + ks * 32 + 8 * lg);
#pragma unroll
      for (int tt = 0; tt < 4; ++tt)
        xf[tt] = *reinterpret_cast<const bf16x8*>(
            &x_lds[tt * 16 + lm][ks * 32 + 8 * lg]);
#pragma unroll
      for (int tt = 0; tt < 4; ++tt)
#pragma unroll
        for (int et = 0; et < 4; ++et)
          acc[tt][et] = __builtin_amdgcn_mfma_f32_16x16x32_bf16(
              xf[tt], wf[et], acc[tt][et], 0, 0, 0);
    }
    size_t rowbase = (size_t)tg * BM;
#pragma unroll
    for (int tt = 0; tt < 4; ++tt)
#pragma unroll
      for (int et = 0; et < 4; ++et)
#pragma unroll
        for (int r = 0; r < 4; ++r) {
          size_t grow = rowbase + tt * 16 + 4 * lg + r;
          kt[grow * DIM + ebase + et * 16 + lm] = f2bf(acc[tt][et][r]);
        }
  } else {  // vt: acc[et][tt], rows = e, cols = tokens
#pragma unroll
    for (int ks = 0; ks < 4; ++ks) {
      bf16x8 wf[4], xf[4];
#pragma unroll
      for (int et = 0; et < 4; ++et)
        wf[et] = *reinterpret_cast<const bf16x8*>(
            Wsrc + (ebase + et * 16 + lm) * DIM + ks * 32 + 8 * lg);
#pragma unroll
      for (int tt = 0; tt < 4; ++tt)
        xf[tt] = *reinterpret_cast<const bf16x8*>(
            &x_lds[tt * 16 + lm][ks * 32 + 8 * lg]);
#pragma unroll
      for (int et = 0; et < 4; ++et)
#pragma unroll
        for (int tt = 0; tt < 4; ++tt)
          acc[et][tt] = __builtin_amdgcn_mfma_f32_16x16x32_bf16(
              wf[et], xf[tt], acc[et][tt], 0, 0, 0);
    }
    int b = tg >> 6;            // 64 blocks per batch
    int nb = (tg & 63) * BM;
#pragma unroll
    for (int et = 0; et < 4; ++et)
#pragma unroll
      for (int tt = 0; tt < 4; ++tt)
#pragma unroll
        for (int r = 0; r < 4; ++r) {
          int e = ebase + et * 16 + 4 * lg + r;
          vt[((size_t)b * DIM + e) * NTOK + nb + tt * 16 + lm] =
              f2bf(acc[et][tt][r]);
        }
  }
}

// ---------------------------------------------------------------------------
// Kernel 3: fused qproj + attention partials, per (batch, 512-token chunk).
// Phase Q: q = SCALE * LN(slots) @ Wq^T -> bf16 LDS
// Phase 1: dots via MFMA (A=q, B=k fragments from global), softmax in-reg
// Phase 2: D partials + N partials (v streamed wide, a_t broadcast reads)
// ---------------------------------------------------------------------------
__global__ __launch_bounds__(256) void k_attn(
    const float* __restrict__ slots, const float* __restrict__ Wq,
    const float* __restrict__ lnw, const float* __restrict__ lnb,
    const unsigned short* __restrict__ kt, const unsigned short* __restrict__ vt,
    float* __restrict__ Np, float* __restrict__ Dp) {
  int bid = blockIdx.x;
  int b = bid >> 3, ch = bid & 7;
  int n0 = ch * CHUNK;
  int t = threadIdx.x;
  __shared__ unsigned short q_lds[NSLOT][LDK];  // 2176 B
  __shared__ __align__(16) float sln[NSLOT][DIM];
  __shared__ __align__(16) float a_t[CHUNK][NSLOT];  // 16 KB

  {  // Phase Q: LN(slots) then q rows; thread = (slot s, lane c)
    int s = t >> 5, c = t & 31;
    const float* sb = slots + (b * NSLOT + s) * DIM;
    float4 xv = *reinterpret_cast<const float4*>(sb + c * 4);
    float ps = xv.x + xv.y + xv.z + xv.w;
    float pq = xv.x * xv.x + xv.y * xv.y + xv.z * xv.z + xv.w * xv.w;
#pragma unroll
    for (int m = 16; m >= 1; m >>= 1) {
      ps += __shfl_xor(ps, m, 32);
      pq += __shfl_xor(pq, m, 32);
    }
    float mean = ps * (1.0f / DIM);
    float var = fmaxf(pq * (1.0f / DIM) - mean * mean, 0.0f);
    float inv = 1.0f / sqrtf(var + LN_EPS);
    float vals[4] = {xv.x, xv.y, xv.z, xv.w};
#pragma unroll
    for (int ii = 0; ii < 4; ++ii) {
      int d = c * 4 + ii;
      sln[s][d] = (vals[ii] - mean) * inv * lnw[d] + lnb[d];
    }
    __syncthreads();
#pragma unroll
    for (int ii = 0; ii < 4; ++ii) {
      int e = c + 32 * ii;
      const float* wr = Wq + e * DIM;
      float acc = 0.0f;
#pragma unroll
      for (int d4 = 0; d4 < DIM / 4; ++d4) {
        float4 w4 = *reinterpret_cast<const float4*>(wr + d4 * 4);
        float4 s4 = *reinterpret_cast<const float4*>(&sln[s][d4 * 4]);
        acc += s4.x * w4.x + s4.y * w4.y + s4.z * w4.z + s4.w * w4.w;
      }
      q_lds[s][e] = f2bf(SCALE * acc);
    }
  }
  __syncthreads();

  {  // Phase 1: MFMA dots + softmax. wave w owns tokens [w*128, w*128+128)
    int w = t >> 6, l = t & 63, lm = l & 15, lg = l >> 4;
    bf16x8 aq[4];
#pragma unroll
    for (int ks = 0; ks < 4; ++ks)
      aq[ks] = *reinterpret_cast<const bf16x8*>(
          &q_lds[lm & 7][ks * 32 + 8 * lg]);
    const unsigned short* kb = kt + ((size_t)b * NTOK + n0) * DIM;
#pragma unroll
    for (int tt8 = 0; tt8 < 8; ++tt8) {
      int tok = w * 128 + tt8 * 16 + lm;  // within chunk
      f32x4 acc = (f32x4){0.f, 0.f, 0.f, 0.f};
#pragma unroll
      for (int ks = 0; ks < 4; ++ks) {
        bf16x8 bk = *reinterpret_cast<const bf16x8*>(
            kb + (size_t)tok * DIM + ks * 32 + 8 * lg);
        acc = __builtin_amdgcn_mfma_f32_16x16x32_bf16(aq[ks], bk, acc, 0, 0, 0);
      }
      // lanes lg<2 hold slots 4*lg+r for token tok
      float m4 = fmaxf(fmaxf(acc[0], acc[1]), fmaxf(acc[2], acc[3]));
      float m8 = fmaxf(m4, __shfl_xor(m4, 16));
      float e0 = expf(acc[0] - m8), e1 = expf(acc[1] - m8);
      float e2 = expf(acc[2] - m8), e3 = expf(acc[3] - m8);
      float s4 = e0 + e1 + e2 + e3;
      float s8 = s4 + __shfl_xor(s4, 16);
      float rs = 1.0f / s8;
      if (lg < 2) {
        float4 av = {e0 * rs + ATT_EPS, e1 * rs + ATT_EPS, e2 * rs + ATT_EPS,
                     e3 * rs + ATT_EPS};
        *reinterpret_cast<float4*>(&a_t[tok][lg * 4]) = av;
      }
    }
  }
  __syncthreads();

  {  // Phase 2a: D partials (sum a_t over tokens per slot)
    int i = t >> 5, c = t & 31;
    float s = 0.0f;
#pragma unroll
    for (int jj = 0; jj < CHUNK / 32; ++jj) s += a_t[c + 32 * jj][i];
#pragma unroll
    for (int m = 16; m >= 1; m >>= 1) s += __shfl_xor(s, m, 32);
    if (c == 0) Dp[(b * NCH + ch) * NSLOT + i] = s;
  }

  {  // Phase 2b: N partials; thread owns (d, group of 4 slots)
    int d = t & (DIM - 1), ig = t >> 7;
    const unsigned short* vb = vt + ((size_t)b * DIM + d) * NTOK + n0;
    float acc0 = 0, acc1 = 0, acc2 = 0, acc3 = 0;
    for (int j8 = 0; j8 < CHUNK / 8; ++j8) {
      ushort8_t vv = *reinterpret_cast<const ushort8_t*>(vb + j8 * 8);
#pragma unroll
      for (int u = 0; u < 8; ++u) {
        float vval = bf2f(vv[u]);
        float4 av = *reinterpret_cast<const float4*>(&a_t[j8 * 8 + u][ig * 4]);
        acc0 += vval * av.x;
        acc1 += vval * av.y;
        acc2 += vval * av.z;
        acc3 += vval * av.w;
      }
    }
    size_t base = (size_t)(b * NCH + ch) * NSLOT;
    Np[(base + ig * 4 + 0) * DIM + d] = acc0;
    Np[(base + ig * 4 + 1) * DIM + d] = acc1;
    Np[(base + ig * 4 + 2) * DIM + d] = acc2;
    Np[(base + ig * 4 + 3) * DIM + d] = acc3;
  }
}

// ---------------------------------------------------------------------------
// Kernel 4: per (batch, slot) block: reduce partials -> update -> GRU -> MLP
// ---------------------------------------------------------------------------
__global__ __launch_bounds__(256) void k_update(
    float* __restrict__ slots, const float* __restrict__ Np,
    const float* __restrict__ Dp, const float* __restrict__ W_ih,
    const float* __restrict__ W_hh, const float* __restrict__ b_ih,
    const float* __restrict__ b_hh, const float* __restrict__ W1,
    const float* __restrict__ b1, const float* __restrict__ W2,
    const float* __restrict__ b2, const float* __restrict__ lnfw,
    const float* __restrict__ lnfb) {
  int bs = blockIdx.x;
  int b = bs >> 3, s = bs & 7;
  int t = threadIdx.x;
  __shared__ __align__(16) float upd[DIM];
  __shared__ __align__(16) float sprev[DIM];
  __shared__ __align__(16) float snew[DIM];
  __shared__ __align__(16) float ffin[DIM];
  __shared__ __align__(16) float ffb[DIM];
  __shared__ __align__(16) float gx[3 * DIM];
  __shared__ __align__(16) float gh[3 * DIM];

  float dsum = 0.0f;
  for (int ch = 0; ch < NCH; ++ch) dsum += Dp[(b * NCH + ch) * NSLOT + s];

  if (t < DIM) {
    sprev[t] = slots[(b * NSLOT + s) * DIM + t];
    float a = 0.0f;
    for (int ch = 0; ch < NCH; ++ch)
      a += Np[((size_t)(b * NCH + ch) * NSLOT + s) * DIM + t];
    upd[t] = a / dsum;
  }
  __syncthreads();

  for (int e = t; e < 3 * DIM; e += 256) {
    const float* wi = W_ih + e * DIM;
    const float* wh = W_hh + e * DIM;
    float ax = 0.0f, ah = 0.0f;
#pragma unroll
    for (int d4 = 0; d4 < DIM / 4; ++d4) {
      float4 u4 = *reinterpret_cast<const float4*>(&upd[d4 * 4]);
      float4 p4 = *reinterpret_cast<const float4*>(&sprev[d4 * 4]);
      float4 wi4 = *reinterpret_cast<const float4*>(wi + d4 * 4);
      float4 wh4 = *reinterpret_cast<const float4*>(wh + d4 * 4);
      ax += u4.x * wi4.x + u4.y * wi4.y + u4.z * wi4.z + u4.w * wi4.w;
      ah += p4.x * wh4.x + p4.y * wh4.y + p4.z * wh4.z + p4.w * wh4.w;
    }
    gx[e] = ax + b_ih[e];
    gh[e] = ah + b_hh[e];
  }
  __syncthreads();

  if (t < DIM) {
    float xr = gx[t], xz = gx[DIM + t], xn = gx[2 * DIM + t];
    float hr = gh[t], hz = gh[DIM + t], hn = gh[2 * DIM + t];
    float r = 1.0f / (1.0f + expf(-(xr + hr)));
    float z = 1.0f / (1.0f + expf(-(xz + hz)));
    float ng = tanhf(xn + r * hn);
    snew[t] = (1.0f - z) * ng + z * sprev[t];
  }
  __syncthreads();

  if (t < DIM) {
    float s1 = 0.0f, s2 = 0.0f;
#pragma unroll 8
    for (int d = 0; d < DIM; ++d) {
      float v = snew[d];
      s1 += v;
      s2 += v * v;
    }
    float mean = s1 * (1.0f / DIM);
    float var = fmaxf(s2 * (1.0f / DIM) - mean * mean, 0.0f);
    float inv = 1.0f / sqrtf(var + LN_EPS);
    ffin[t] = (snew[t] - mean) * inv * lnfw[t] + lnfb[t];
  }
  __syncthreads();

  if (t < DIM) {
    const float* wr = W1 + t * DIM;
    float acc = 0.0f;
#pragma unroll
    for (int d4 = 0; d4 < DIM / 4; ++d4) {
      float4 f4 = *reinterpret_cast<const float4*>(&ffin[d4 * 4]);
      float4 w4 = *reinterpret_cast<const float4*>(wr + d4 * 4);
      acc += f4.x * w4.x + f4.y * w4.y + f4.z * w4.z + f4.w * w4.w;
    }
    ffb[t] = fmaxf(acc + b1[t], 0.0f);
  }
  __syncthreads();

  if (t < DIM) {
    const float* wr = W2 + t * DIM;
    float acc = 0.0f;
#pragma unroll
    for (int h4 = 0; h4 < DIM / 4; ++h4) {
      float4 f4 = *reinterpret_cast<const float4*>(&ffb[h4 * 4]);
      float4 w4 = *reinterpret_cast<const float4*>(wr + h4 * 4);
      acc += f4.x * w4.x + f4.y * w4.y + f4.z * w4.z + f4.w * w4.w;
    }
    slots[(b * NSLOT + s) * DIM + t] = snew[t] + acc + b2[t];
  }
}

__global__ __launch_bounds__(256) void k_sentinel(float* __restrict__ out,
                                                  int n) {
  int i = blockIdx.x * blockDim.x + threadIdx.x;
  if (i < n) out[i] = 1234.5f;
}

// ---------------------------------------------------------------------------
extern "C" void kernel_launch(void* const* d_in, const int* in_sizes, int n_in,
                              void* d_out, int out_size, void* d_ws,
                              size_t ws_size, hipStream_t stream) {
  const float* inp = (const float*)d_in[0];
  const float* mu = (const float*)d_in[1];
  const float* lsig = (const float*)d_in[2];
  const float* Wq = (const float*)d_in[3];
  const float* Wk = (const float*)d_in[4];
  const float* Wv = (const float*)d_in[5];
  const float* W_ih = (const float*)d_in[6];
  const float* W_hh = (const float*)d_in[7];
  const float* b_ih = (const float*)d_in[8];
  const float* b_hh = (const float*)d_in[9];
  const float* W1 = (const float*)d_in[10];
  const float* b1 = (const float*)d_in[11];
  const float* W2 = (const float*)d_in[12];
  const float* b2 = (const float*)d_in[13];
  const float* ln_in_w = (const float*)d_in[14];
  const float* ln_in_b = (const float*)d_in[15];
  const float* ln_s_w = (const float*)d_in[16];
  const float* ln_s_b = (const float*)d_in[17];
  const float* ln_ff_w = (const float*)d_in[18];
  const float* ln_ff_b = (const float*)d_in[19];

  float* slots = (float*)d_out;

  // ws layout: kt bf16 [b][n][d] | vt bf16 [b][d][n] | Wbf bf16 | Np f32 | Dp f32
  const size_t kv_elems = (size_t)NB * DIM * NTOK;
  const size_t w_elems = (size_t)2 * DIM * DIM;
  const size_t np_elems = (size_t)NB * NCH * NSLOT * DIM;
  const size_t dp_elems = (size_t)NB * NCH * NSLOT;
  size_t need = kv_elems * 2 * 2 + w_elems * 2 + np_elems * 4 + dp_elems * 4;
  if (ws_size < need) {
    k_sentinel<<<(out_size + 255) / 256, 256, 0, stream>>>((float*)d_out,
                                                           out_size);
    return;
  }
  char* wsb = (char*)d_ws;
  unsigned short* kt = (unsigned short*)wsb;
  unsigned short* vt = kt + kv_elems;
  unsigned short* Wbf = vt + kv_elems;
  float* Np = (float*)(wsb + kv_elems * 4 + w_elems * 2);
  float* Dp = Np + np_elems;

  k_init_slots<<<(NB * NSLOT * DIM) / 256, 256, 0, stream>>>(mu, lsig, slots);
  k_wcast<<<(DIM * DIM) / 256, 256, 0, stream>>>(Wk, Wv, Wbf);
  k_ln_kv<<<NB * NTOK / BM, 256, 0, stream>>>(inp, Wbf, ln_in_w, ln_in_b, kt,
                                              vt);
  for (int it = 0; it < 3; ++it) {
    k_attn<<<NB * NCH, 256, 0, stream>>>(slots, Wq, ln_s_w, ln_s_b, kt, vt, Np,
                                         Dp);
    k_update<<<NB * NSLOT, 256, 0, stream>>>(slots, Np, Dp, W_ih, W_hh, b_ih,
                                             b_hh, W1, b1, W2, b2, ln_ff_w,
                                             ln_ff_b);
  }
}